// Round 2
// baseline (782.178 us; speedup 1.0000x reference)
//
#include <hip/hip_runtime.h>
#include <stdint.h>

#define NB   16
#define HH   256
#define C    14
#define CX   17      // C+3
#define PERC 51
#define HID  256

// ---------------- threefry2x32 (JAX-compatible, 20 rounds) ----------------
__device__ __forceinline__ void tf_round(uint32_t& x0, uint32_t& x1, int r) {
  x0 += x1; x1 = (x1 << r) | (x1 >> (32 - r)); x1 ^= x0;
}
__device__ __forceinline__ void threefry2x32(uint32_t k0, uint32_t k1,
                                             uint32_t& x0, uint32_t& x1) {
  const uint32_t ks2 = k0 ^ k1 ^ 0x1BD11BDAu;
  x0 += k0; x1 += k1;
  tf_round(x0,x1,13); tf_round(x0,x1,15); tf_round(x0,x1,26); tf_round(x0,x1,6);
  x0 += k1; x1 += ks2 + 1u;
  tf_round(x0,x1,17); tf_round(x0,x1,29); tf_round(x0,x1,16); tf_round(x0,x1,24);
  x0 += ks2; x1 += k0 + 2u;
  tf_round(x0,x1,13); tf_round(x0,x1,15); tf_round(x0,x1,26); tf_round(x0,x1,6);
  x0 += k0; x1 += k1 + 3u;
  tf_round(x0,x1,17); tf_round(x0,x1,29); tf_round(x0,x1,16); tf_round(x0,x1,24);
  x0 += k1; x1 += ks2 + 4u;
  tf_round(x0,x1,13); tf_round(x0,x1,15); tf_round(x0,x1,26); tf_round(x0,x1,6);
  x0 += ks2; x1 += k0 + 5u;
}
// upd = (uniform(fold_in(key(0),1234), (B,H,W,1)) <= 0.5) ? 1 : 0
// JAX threefry_partitionable=True (modern default): element i uses 64-bit
// counter i -> threefry2x32(key, (hi32(i), lo32(i))), sample = out0 ^ out1.
__device__ __forceinline__ float upd_val(uint32_t gpix) {
  uint32_t fk0 = 0u, fk1 = 1234u;
  threefry2x32(0u, 0u, fk0, fk1);   // fold_in(key(0), 1234): key applied to (0,1234)
  uint32_t a = 0u, b = gpix;        // (counter >> 32, counter & 0xffffffff)
  threefry2x32(fk0, fk1, a, b);
  const uint32_t bits = a ^ b;
  const float u = __uint_as_float((bits >> 9) | 0x3f800000u) - 1.0f;
  return (u <= 0.5f) ? 1.0f : 0.0f;
}

// ---------------- kernel 0: transpose W2 (256x14) -> w2t (16x256, zero-pad) --
__global__ void nca_prep(const float* __restrict__ W2, float* __restrict__ w2t) {
  const int t = threadIdx.x;  // 256 threads, one hidden unit each
  #pragma unroll
  for (int co = 0; co < 16; ++co)
    w2t[co * 256 + t] = (co < C) ? W2[t * C + co] : 0.0f;
}

// ---------------- kernel 1: fused NCA step (8x8 pixel tile / block) ---------
#define XC(r_, c_, ch_) xc[(((r_) * 10 + (c_)) * CX) + (ch_)]

__global__ __launch_bounds__(256, 2)
void nca_main(const float* __restrict__ x,  const float* __restrict__ img,
              const float* __restrict__ W1, const float* __restrict__ b1,
              const float* __restrict__ b2, const float* __restrict__ w2t,
              float* __restrict__ out, float* __restrict__ plane) {
  __shared__ float xc[10 * 10 * CX];   // input tile + halo (x ‖ imagen), 6800 B
  __shared__ float hbuf[64 * 256];     // hidden, XOR-swizzled, 64 KiB
  __shared__ float updf[64];

  const int t    = threadIdx.x;
  const int bid  = blockIdx.x;
  const int bb   = bid >> 10;          // batch
  const int tile = bid & 1023;
  const int row0 = (tile >> 5) << 3, col0 = (tile & 31) << 3;

  // ---- stage xc halo tile (zero-padded; zero-pad is equivalent to NEG_INF
  //      for the >0.1 alive test, and correct for SAME conv) ----
  for (int e = t; e < 10 * 10 * CX; e += 256) {
    const int r   = e / (10 * CX);
    const int rem = e - r * (10 * CX);
    const int cl  = rem / CX;
    const int ch  = rem - cl * CX;
    const int gr = row0 + r - 1, gc = col0 + cl - 1;
    float v = 0.0f;
    if ((unsigned)gr < 256u && (unsigned)gc < 256u) {
      v = (ch < C) ? x[(((size_t)bb * 256 + gr) * 256 + gc) * C + ch]
                   : img[((size_t)gr * 256 + gc) * 3 + (ch - C)];
    }
    xc[e] = v;
  }
  __syncthreads();

  const int p  = t & 63;               // pixel within tile
  const int pr = p >> 3, pc = p & 7;

  if (t < 64) {  // wave 0 computes the stochastic update mask
    const uint32_t gpix = ((uint32_t)bb * 256u + (row0 + pr)) * 256u + (col0 + pc);
    updf[t] = upd_val(gpix);
  }

  // ---- perception: 51 values for this thread's pixel, in registers ----
  float pe[PERC];
  #pragma unroll
  for (int c = 0; c < CX; ++c) {
    const float a00 = XC(pr+0, pc+0, c), a01 = XC(pr+0, pc+1, c), a02 = XC(pr+0, pc+2, c);
    const float a10 = XC(pr+1, pc+0, c), a11 = XC(pr+1, pc+1, c), a12 = XC(pr+1, pc+2, c);
    const float a20 = XC(pr+2, pc+0, c), a21 = XC(pr+2, pc+1, c), a22 = XC(pr+2, pc+2, c);
    pe[3*c+0] = a11;
    pe[3*c+1] = ((a02 - a00) + 2.0f*(a12 - a10) + (a22 - a20)) * 0.125f; // Sobel-x
    pe[3*c+2] = ((a20 - a00) + 2.0f*(a21 - a01) + (a22 - a02)) * 0.125f; // Sobel-y
  }

  // ---- GEMM1: h[p][qu*64 .. qu*64+63] = relu(pe @ W1 + b1) ----
  // wave-uniform hidden-quarter -> W1/b1 loads scalarize (s_load, no LDS)
  const int qu = __builtin_amdgcn_readfirstlane(t >> 6);
  const float* __restrict__ w1b = W1 + qu * 64;
  const float* __restrict__ b1b = b1 + qu * 64;
  const int hbase = p * 256;
  const int sw    = (p & 7) << 2;      // float-index XOR swizzle (16B granules)
  #pragma unroll 2
  for (int db = 0; db < 16; ++db) {
    const int d0 = db * 4;
    float4 acc = *(const float4*)(b1b + d0);
    #pragma unroll
    for (int c = 0; c < PERC; ++c) {
      const float4 w = *(const float4*)(w1b + (size_t)c * HID + d0);
      acc.x = fmaf(pe[c], w.x, acc.x);
      acc.y = fmaf(pe[c], w.y, acc.y);
      acc.z = fmaf(pe[c], w.z, acc.z);
      acc.w = fmaf(pe[c], w.w, acc.w);
    }
    acc.x = fmaxf(acc.x, 0.0f); acc.y = fmaxf(acc.y, 0.0f);
    acc.z = fmaxf(acc.z, 0.0f); acc.w = fmaxf(acc.w, 0.0f);
    *(float4*)&hbuf[hbase + ((qu * 64 + d0) ^ sw)] = acc;
  }
  __syncthreads();

  // ---- GEMM2: dx[p][co0..co0+3] = h[p][:] @ W2 + b2 ----
  const int co0 = qu * 4;
  const float* __restrict__ w2r0 = w2t + (size_t)(co0 + 0) * 256;
  const float* __restrict__ w2r1 = w2t + (size_t)(co0 + 1) * 256;
  const float* __restrict__ w2r2 = w2t + (size_t)(co0 + 2) * 256;
  const float* __restrict__ w2r3 = w2t + (size_t)(co0 + 3) * 256;
  float a0 = (co0 + 0 < C) ? b2[co0 + 0] : 0.0f;
  float a1 = (co0 + 1 < C) ? b2[co0 + 1] : 0.0f;
  float a2 = (co0 + 2 < C) ? b2[co0 + 2] : 0.0f;
  float a3 = (co0 + 3 < C) ? b2[co0 + 3] : 0.0f;
  #pragma unroll 8
  for (int dq = 0; dq < 64; ++dq) {
    const float4 hv = *(float4*)&hbuf[hbase + ((dq * 4) ^ sw)];
    const float4 w0 = *(const float4*)(w2r0 + dq * 4);
    const float4 w1v = *(const float4*)(w2r1 + dq * 4);
    const float4 w2v = *(const float4*)(w2r2 + dq * 4);
    const float4 w3v = *(const float4*)(w2r3 + dq * 4);
    a0 = fmaf(hv.x, w0.x, a0); a0 = fmaf(hv.y, w0.y, a0);
    a0 = fmaf(hv.z, w0.z, a0); a0 = fmaf(hv.w, w0.w, a0);
    a1 = fmaf(hv.x, w1v.x, a1); a1 = fmaf(hv.y, w1v.y, a1);
    a1 = fmaf(hv.z, w1v.z, a1); a1 = fmaf(hv.w, w1v.w, a1);
    a2 = fmaf(hv.x, w2v.x, a2); a2 = fmaf(hv.y, w2v.y, a2);
    a2 = fmaf(hv.z, w2v.z, a2); a2 = fmaf(hv.w, w2v.w, a2);
    a3 = fmaf(hv.x, w3v.x, a3); a3 = fmaf(hv.y, w3v.y, a3);
    a3 = fmaf(hv.z, w3v.z, a3); a3 = fmaf(hv.w, w3v.w, a3);
  }

  // ---- epilogue: x_new = x + 0.1 * dx * upd ----
  const float scale = 0.1f * updf[p];
  const int gr = row0 + pr, gc = col0 + pc;
  const uint32_t gpix = ((uint32_t)bb * 256u + gr) * 256u + gc;
  float* __restrict__ op = out + (size_t)gpix * C + co0;
  const int xcb = ((pr + 1) * 10 + (pc + 1)) * CX;
  if (qu < 3) {
    const float r0 = xc[xcb + co0 + 0] + a0 * scale;
    const float r1 = xc[xcb + co0 + 1] + a1 * scale;
    const float r2 = xc[xcb + co0 + 2] + a2 * scale;
    const float r3 = xc[xcb + co0 + 3] + a3 * scale;
    *(float2*)(op + 0) = make_float2(r0, r1);
    *(float2*)(op + 2) = make_float2(r2, r3);
    if (qu == 0) plane[gpix] = r0;   // new ch0 for the post-update alive pool
  } else {
    const float r0 = xc[xcb + 12] + a0 * scale;
    const float r1 = xc[xcb + 13] + a1 * scale;
    *(float2*)(op + 0) = make_float2(r0, r1);
  }
}

// ---------------- kernel 2: alive masking (16x16 tile / block) --------------
__global__ __launch_bounds__(256)
void nca_mask(const float* __restrict__ x, const float* __restrict__ plane,
              float* __restrict__ out) {
  __shared__ float sN[18 * 18];  // new ch0 halo
  __shared__ float sO[18 * 18];  // orig ch0 halo
  const int t    = threadIdx.x;
  const int bid  = blockIdx.x;
  const int bb   = bid >> 8;
  const int tile = bid & 255;
  const int row0 = (tile >> 4) << 4, col0 = (tile & 15) << 4;

  for (int e = t; e < 18 * 18; e += 256) {
    const int r = e / 18, c = e - r * 18;
    const int gr = row0 + r - 1, gc = col0 + c - 1;
    float vn = 0.0f, vo = 0.0f;
    if ((unsigned)gr < 256u && (unsigned)gc < 256u) {
      const size_t gp = ((size_t)bb * 256 + gr) * 256 + gc;
      vn = plane[gp];
      vo = x[gp * C];
    }
    sN[e] = vn; sO[e] = vo;
  }
  __syncthreads();

  const int pr = t >> 4, pc = t & 15;
  float mn = -1e30f, mo = -1e30f;
  #pragma unroll
  for (int i = 0; i < 3; ++i)
    #pragma unroll
    for (int j = 0; j < 3; ++j) {
      mn = fmaxf(mn, sN[(pr + i) * 18 + pc + j]);
      mo = fmaxf(mo, sO[(pr + i) * 18 + pc + j]);
    }
  const bool alive = (mo > 0.1f) && (mn > 0.1f);
  if (!alive) {
    const size_t gp = ((size_t)bb * 256 + row0 + pr) * 256 + col0 + pc;
    float* __restrict__ o = out + gp * C;
    const float2 z = make_float2(0.0f, 0.0f);
    #pragma unroll
    for (int k = 0; k < 7; ++k) ((float2*)o)[k] = z;
  }
}

// ---------------- launch ----------------------------------------------------
extern "C" void kernel_launch(void* const* d_in, const int* in_sizes, int n_in,
                              void* d_out, int out_size, void* d_ws, size_t ws_size,
                              hipStream_t stream) {
  const float* x  = (const float*)d_in[0];
  const float* im = (const float*)d_in[1];
  const float* W1 = (const float*)d_in[2];
  const float* b1 = (const float*)d_in[3];
  const float* W2 = (const float*)d_in[4];
  const float* b2 = (const float*)d_in[5];
  float* out   = (float*)d_out;
  float* plane = (float*)d_ws;                    // 1,048,576 floats (4 MiB)
  float* w2t   = (float*)d_ws + 1048576;          // 16*256 floats

  nca_prep<<<1,    256, 0, stream>>>(W2, w2t);
  nca_main<<<16384, 256, 0, stream>>>(x, im, W1, b1, b2, w2t, out, plane);
  nca_mask<<<4096, 256, 0, stream>>>(x, plane, out);
}

// Round 3
// 106.321 us; speedup vs baseline: 7.3568x; 7.3568x over previous
//
#include <hip/hip_runtime.h>
#include <stdint.h>

#define C    14
#define CX   17      // C+3
#define PERC 51
#define HID  256

typedef __attribute__((ext_vector_type(4))) short  bf16x4;
typedef __attribute__((ext_vector_type(8))) short  bf16x8;
typedef __attribute__((ext_vector_type(4))) float  f32x4;
typedef __attribute__((ext_vector_type(8))) unsigned short u16x8;

// ---------------- bf16 helpers ----------------
__device__ __forceinline__ float bfu(unsigned short u) {
  return __uint_as_float(((uint32_t)u) << 16);
}
__device__ __forceinline__ unsigned short bf16r(float f) {  // RNE
  uint32_t u = __float_as_uint(f);
  return (unsigned short)((u + 0x7fffu + ((u >> 16) & 1u)) >> 16);
}

// ---------------- MFMA wrappers ----------------
__device__ __forceinline__ f32x4 mfma32(bf16x8 a, bf16x8 b, f32x4 c) {
  return __builtin_amdgcn_mfma_f32_16x16x32_bf16(a, b, c, 0, 0, 0);
}
#if __has_builtin(__builtin_amdgcn_mfma_f32_16x16x16bf16_1k)
#define HAVE_MFMA16_BUILTIN 1
#endif
__device__ __forceinline__ f32x4 mfma16(bf16x4 a, bf16x4 b, f32x4 c) {
#ifdef HAVE_MFMA16_BUILTIN
  return __builtin_amdgcn_mfma_f32_16x16x16bf16_1k(a, b, c, 0, 0, 0);
#else
  asm volatile("v_mfma_f32_16x16x16_bf16 %0, %1, %2, %0" : "+v"(c) : "v"(a), "v"(b));
  return c;
#endif
}

// ---------------- threefry2x32 (JAX partitionable) ----------------
__device__ __forceinline__ void tf_round(uint32_t& x0, uint32_t& x1, int r) {
  x0 += x1; x1 = (x1 << r) | (x1 >> (32 - r)); x1 ^= x0;
}
__device__ __forceinline__ void threefry2x32(uint32_t k0, uint32_t k1,
                                             uint32_t& x0, uint32_t& x1) {
  const uint32_t ks2 = k0 ^ k1 ^ 0x1BD11BDAu;
  x0 += k0; x1 += k1;
  tf_round(x0,x1,13); tf_round(x0,x1,15); tf_round(x0,x1,26); tf_round(x0,x1,6);
  x0 += k1; x1 += ks2 + 1u;
  tf_round(x0,x1,17); tf_round(x0,x1,29); tf_round(x0,x1,16); tf_round(x0,x1,24);
  x0 += ks2; x1 += k0 + 2u;
  tf_round(x0,x1,13); tf_round(x0,x1,15); tf_round(x0,x1,26); tf_round(x0,x1,6);
  x0 += k0; x1 += k1 + 3u;
  tf_round(x0,x1,17); tf_round(x0,x1,29); tf_round(x0,x1,16); tf_round(x0,x1,24);
  x0 += k1; x1 += ks2 + 4u;
  tf_round(x0,x1,13); tf_round(x0,x1,15); tf_round(x0,x1,26); tf_round(x0,x1,6);
  x0 += ks2; x1 += k0 + 5u;
}
__device__ __forceinline__ float upd_val(uint32_t gpix) {
  uint32_t fk0 = 0u, fk1 = 1234u;
  threefry2x32(0u, 0u, fk0, fk1);
  uint32_t a = 0u, b = gpix;
  threefry2x32(fk0, fk1, a, b);
  const uint32_t bits = a ^ b;
  const float u = __uint_as_float((bits >> 9) | 0x3f800000u) - 1.0f;
  return (u <= 0.5f) ? 1.0f : 0.0f;
}

// ---------------- kernel 0: weight fragment prep ----------------
// w1f: A-frags of W1^T for mfma_16x16x32: [mt 0..15][k2 0..1][lane][8]
//   value = W1[k][hidden], hidden = mt*16 + (l&15), k = k2*32 + (l>>4)*8 + j (0 for k>=51)
// w2f: A-frags of W2^T for mfma_16x16x16: [ks 0..15][lane][4]
//   value = W2[k][co], co = l&15 (<14 else 0), k = ks*16 + (l>>4)*4 + j
__global__ void nca_prep(const float* __restrict__ W1, const float* __restrict__ W2,
                         const float* __restrict__ b2,
                         unsigned short* __restrict__ w1fu,
                         unsigned short* __restrict__ w2fu,
                         float* __restrict__ b2p) {
  const int bid = blockIdx.x, t = threadIdx.x;
  if (bid < 64) {
    const int f = bid * 256 + t;                 // 0..16383
    const int j = f & 7, l = (f >> 3) & 63, k2 = (f >> 9) & 1, mt = f >> 10;
    const int n = mt * 16 + (l & 15);
    const int k = k2 * 32 + ((l >> 4) & 3) * 8 + j;
    const float v = (k < PERC) ? W1[k * HID + n] : 0.0f;
    w1fu[f] = bf16r(v);
  } else if (bid < 80) {
    const int f = (bid - 64) * 256 + t;          // 0..4095
    const int j = f & 3, l = (f >> 2) & 63, ks = f >> 8;
    const int co = l & 15;
    const int k = ks * 16 + ((l >> 4) & 3) * 4 + j;
    const float v = (co < C) ? W2[k * C + co] : 0.0f;
    w2fu[f] = bf16r(v);
  } else if (t < 16) {
    b2p[t] = (t < C) ? b2[t] : 0.0f;
  }
}

// ---------------- kernel 1: fused NCA step (16x16 pixel tile) ----------------
__global__ __launch_bounds__(256, 2)
void nca_main(const float* __restrict__ x, const float* __restrict__ img,
              const float* __restrict__ b1,
              const unsigned short* __restrict__ w1fu,
              const unsigned short* __restrict__ w2fu,
              const float* __restrict__ b2p,
              float* __restrict__ out, float* __restrict__ plane) {
  __shared__ unsigned short xcs[18 * 18 * 24];  // bf16 halo tile, ch padded to 24
  __shared__ unsigned short Ps[256 * 64];       // perception, XOR-swizzled 16B granules
  __shared__ float updf[256];

  const int t    = threadIdx.x;
  const int bid  = blockIdx.x;
  const int bb   = bid >> 8;
  const int tile = bid & 255;
  const int row0 = (tile >> 4) << 4, col0 = (tile & 15) << 4;

  // ---- stage xc halo (bf16, zero-padded borders) ----
  for (int e = t; e < 324; e += 256) {
    const int r = e / 18, c = e - r * 18;
    const int gr = row0 + r - 1, gc = col0 + c - 1;
    uint32_t w[8]; unsigned short w16;
    if ((unsigned)gr < 256u && (unsigned)gc < 256u) {
      const size_t gp = (size_t)bb * 65536 + (size_t)gr * 256 + gc;
      const float* xp = x + gp * C;
      float v[17];
      #pragma unroll
      for (int k = 0; k < 7; ++k) {
        const float2 f2 = *(const float2*)(xp + 2 * k);
        v[2 * k] = f2.x; v[2 * k + 1] = f2.y;
      }
      const float* ip = img + ((size_t)gr * 256 + gc) * 3;
      v[14] = ip[0]; v[15] = ip[1]; v[16] = ip[2];
      #pragma unroll
      for (int k = 0; k < 8; ++k)
        w[k] = (uint32_t)bf16r(v[2 * k]) | ((uint32_t)bf16r(v[2 * k + 1]) << 16);
      w16 = bf16r(v[16]);
    } else {
      #pragma unroll
      for (int k = 0; k < 8; ++k) w[k] = 0u;
      w16 = 0;
    }
    uint32_t* d = (uint32_t*)&xcs[e * 24];
    #pragma unroll
    for (int k = 0; k < 8; ++k) d[k] = w[k];
    xcs[e * 24 + 16] = w16;
  }

  // ---- stochastic update mask (one pixel per thread) ----
  {
    const uint32_t g = ((uint32_t)bb * 256u + (uint32_t)(row0 + (t >> 4))) * 256u
                       + (uint32_t)(col0 + (t & 15));
    updf[t] = upd_val(g);
  }
  __syncthreads();

  // ---- perception (pixel t), pack bf16, store swizzled to Ps ----
  const int pr = t >> 4, pc = t & 15;
  float pe[64];
  #pragma unroll
  for (int h = 0; h < 2; ++h) {
    u16x8 nb[9];
    #pragma unroll
    for (int i = 0; i < 3; ++i)
      #pragma unroll
      for (int j = 0; j < 3; ++j)
        nb[i * 3 + j] = *(const u16x8*)&xcs[((pr + i) * 18 + (pc + j)) * 24 + h * 8];
    #pragma unroll
    for (int cc = 0; cc < 8; ++cc) {
      const int ch = h * 8 + cc;
      const float a00 = bfu(nb[0][cc]), a01 = bfu(nb[1][cc]), a02 = bfu(nb[2][cc]);
      const float a10 = bfu(nb[3][cc]), a11 = bfu(nb[4][cc]), a12 = bfu(nb[5][cc]);
      const float a20 = bfu(nb[6][cc]), a21 = bfu(nb[7][cc]), a22 = bfu(nb[8][cc]);
      pe[3 * ch + 0] = a11;
      pe[3 * ch + 1] = ((a02 - a00) + 2.0f * (a12 - a10) + (a22 - a20)) * 0.125f;
      pe[3 * ch + 2] = ((a20 - a00) + 2.0f * (a21 - a01) + (a22 - a02)) * 0.125f;
    }
  }
  {
    float a[9];
    #pragma unroll
    for (int i = 0; i < 3; ++i)
      #pragma unroll
      for (int j = 0; j < 3; ++j)
        a[i * 3 + j] = bfu(xcs[((pr + i) * 18 + (pc + j)) * 24 + 16]);
    pe[48] = a[4];
    pe[49] = ((a[2] - a[0]) + 2.0f * (a[5] - a[3]) + (a[8] - a[6])) * 0.125f;
    pe[50] = ((a[6] - a[0]) + 2.0f * (a[7] - a[1]) + (a[8] - a[2])) * 0.125f;
  }
  #pragma unroll
  for (int k = PERC; k < 64; ++k) pe[k] = 0.0f;
  #pragma unroll
  for (int g = 0; g < 8; ++g) {
    u16x8 v;
    #pragma unroll
    for (int j = 0; j < 8; ++j) v[j] = bf16r(pe[g * 8 + j]);
    *(u16x8*)&Ps[(t << 6) + ((g ^ (t & 7)) << 3)] = v;
  }
  __syncthreads();

  // ---- GEMMs: wave w owns pixels w*64..w*64+63 ----
  const int lane = t & 63;
  const int wv   = t >> 6;
  const int wbase = wv << 6;
  const int lg = lane >> 4;    // lane group (k-group / row-group)
  const int lc = lane & 15;    // pixel-within-16 (MFMA col)

  f32x4 dxacc[4];
  {
    const float4 b2v = *(const float4*)(b2p + lg * 4);
    #pragma unroll
    for (int nt = 0; nt < 4; ++nt)
      dxacc[nt] = (f32x4){b2v.x, b2v.y, b2v.z, b2v.w};
  }

  #pragma unroll
  for (int nc = 0; nc < 4; ++nc) {          // hidden 64-chunk
    bf16x8 aF[4][2];
    #pragma unroll
    for (int m4 = 0; m4 < 4; ++m4)
      #pragma unroll
      for (int k2 = 0; k2 < 2; ++k2)
        aF[m4][k2] = *(const bf16x8*)(w1fu + (((((nc * 4 + m4) * 2 + k2) * 64) + lane) << 3));

    f32x4 acc[4][4];
    #pragma unroll
    for (int m4 = 0; m4 < 4; ++m4) {
      const float4 b1v = *(const float4*)(b1 + nc * 64 + m4 * 16 + lg * 4);
      #pragma unroll
      for (int nt = 0; nt < 4; ++nt)
        acc[m4][nt] = (f32x4){b1v.x, b1v.y, b1v.z, b1v.w};
    }

    #pragma unroll
    for (int nt = 0; nt < 4; ++nt) {
      const int pix = wbase + nt * 16 + lc;
      const bf16x8 bF0 = *(const bf16x8*)&Ps[(pix << 6) + ((lg ^ (pix & 7)) << 3)];
      const bf16x8 bF1 = *(const bf16x8*)&Ps[(pix << 6) + (((4 + lg) ^ (pix & 7)) << 3)];
      #pragma unroll
      for (int m4 = 0; m4 < 4; ++m4) acc[m4][nt] = mfma32(aF[m4][0], bF0, acc[m4][nt]);
      #pragma unroll
      for (int m4 = 0; m4 < 4; ++m4) acc[m4][nt] = mfma32(aF[m4][1], bF1, acc[m4][nt]);
    }

    // GEMM2 partial: relu + bf16 cast feeds the K=16 MFMA directly
    #pragma unroll
    for (int m4 = 0; m4 < 4; ++m4) {
      const bf16x4 wf = *(const bf16x4*)(w2fu + ((((nc * 4 + m4) * 64) + lane) << 2));
      #pragma unroll
      for (int nt = 0; nt < 4; ++nt) {
        bf16x4 hh;
        #pragma unroll
        for (int j = 0; j < 4; ++j)
          hh[j] = (short)bf16r(fmaxf(acc[m4][nt][j], 0.0f));
        dxacc[nt] = mfma16(wf, hh, dxacc[nt]);
      }
    }
  }
#ifndef HAVE_MFMA16_BUILTIN
  asm volatile("s_nop 7\n\ts_nop 7" :::);
#endif

  // ---- epilogue: x_new = x + 0.1 * dx * upd ----
  #pragma unroll
  for (int nt = 0; nt < 4; ++nt) {
    const int pix = wbase + nt * 16 + lc;
    const float sc = 0.1f * updf[pix];
    const int gr = row0 + (pix >> 4), gc = col0 + (pix & 15);
    const size_t gp = (size_t)bb * 65536 + (size_t)gr * 256 + gc;
    const float* xp = x + gp * C + lg * 4;
    float* op = out + gp * C + lg * 4;
    const f32x4 d = dxacc[nt];
    if (lg < 3) {
      const float2 u0 = *(const float2*)xp;
      const float2 u1 = *(const float2*)(xp + 2);
      const float r0 = u0.x + d[0] * sc, r1 = u0.y + d[1] * sc;
      const float r2 = u1.x + d[2] * sc, r3 = u1.y + d[3] * sc;
      *(float2*)op = make_float2(r0, r1);
      *(float2*)(op + 2) = make_float2(r2, r3);
      if (lg == 0) plane[gp] = r0;
    } else {
      const float2 u0 = *(const float2*)xp;
      *(float2*)op = make_float2(u0.x + d[0] * sc, u0.y + d[1] * sc);
    }
  }
}

// ---------------- kernel 2: alive masking (16x16 tile) ----------------
__global__ __launch_bounds__(256)
void nca_mask(const float* __restrict__ x, const float* __restrict__ plane,
              float* __restrict__ out) {
  __shared__ float sN[18 * 18];
  __shared__ float sO[18 * 18];
  const int t    = threadIdx.x;
  const int bid  = blockIdx.x;
  const int bb   = bid >> 8;
  const int tile = bid & 255;
  const int row0 = (tile >> 4) << 4, col0 = (tile & 15) << 4;

  for (int e = t; e < 18 * 18; e += 256) {
    const int r = e / 18, c = e - r * 18;
    const int gr = row0 + r - 1, gc = col0 + c - 1;
    float vn = 0.0f, vo = 0.0f;
    if ((unsigned)gr < 256u && (unsigned)gc < 256u) {
      const size_t gp = ((size_t)bb * 256 + gr) * 256 + gc;
      vn = plane[gp];
      vo = x[gp * C];
    }
    sN[e] = vn; sO[e] = vo;
  }
  __syncthreads();

  const int pr = t >> 4, pc = t & 15;
  float mn = -1e30f, mo = -1e30f;
  #pragma unroll
  for (int i = 0; i < 3; ++i)
    #pragma unroll
    for (int j = 0; j < 3; ++j) {
      mn = fmaxf(mn, sN[(pr + i) * 18 + pc + j]);
      mo = fmaxf(mo, sO[(pr + i) * 18 + pc + j]);
    }
  const bool alive = (mo > 0.1f) && (mn > 0.1f);
  if (!alive) {
    const size_t gp = ((size_t)bb * 256 + row0 + pr) * 256 + col0 + pc;
    float* __restrict__ o = out + gp * C;
    const float2 z = make_float2(0.0f, 0.0f);
    #pragma unroll
    for (int k = 0; k < 7; ++k) ((float2*)o)[k] = z;
  }
}

// ---------------- launch ----------------
extern "C" void kernel_launch(void* const* d_in, const int* in_sizes, int n_in,
                              void* d_out, int out_size, void* d_ws, size_t ws_size,
                              hipStream_t stream) {
  const float* x  = (const float*)d_in[0];
  const float* im = (const float*)d_in[1];
  const float* W1 = (const float*)d_in[2];
  const float* b1 = (const float*)d_in[3];
  const float* W2 = (const float*)d_in[4];
  const float* b2 = (const float*)d_in[5];
  float* out   = (float*)d_out;
  float* plane = (float*)d_ws;                                   // 4 MiB
  unsigned short* w1fu = (unsigned short*)((char*)d_ws + 4194304);        // 32 KiB
  unsigned short* w2fu = (unsigned short*)((char*)d_ws + 4194304 + 32768); // 8 KiB
  float* b2p = (float*)((char*)d_ws + 4194304 + 32768 + 8192);   // 64 B

  nca_prep<<<81,   256, 0, stream>>>(W1, W2, b2, w1fu, w2fu, b2p);
  nca_main<<<4096, 256, 0, stream>>>(x, im, b1, w1fu, w2fu, b2p, out, plane);
  nca_mask<<<4096, 256, 0, stream>>>(x, plane, out);
}